// Round 1
// baseline (1628.268 us; speedup 1.0000x reference)
//
#include <hip/hip_runtime.h>

#define F 128
#define LEAK 0.2f

// ---------- helpers ----------
__device__ inline void atomicMaxF(float* addr, float val) {
  // works for all non-NaN floats; init must be -inf (0xFF800000)
  if (val >= 0.0f) atomicMax((int*)addr, __float_as_int(val));
  else             atomicMin((unsigned int*)addr, __float_as_uint(val));
}

// fetch (src,dst) for concat([edges, self-loops]) edge i
__device__ inline void edge_sd(const int* ei, int i, int E, int is64, int& s, int& d) {
  if (i < E) {
    if (is64) {
      const long long* e64 = (const long long*)ei;
      s = (int)e64[i]; d = (int)e64[E + i];
    } else {
      s = ei[i]; d = ei[E + i];
    }
  } else {
    s = d = i - E;
  }
}

#define FMA4(A, XS, WV) \
  A.x = fmaf(XS, WV.x, A.x); A.y = fmaf(XS, WV.y, A.y); \
  A.z = fmaf(XS, WV.z, A.z); A.w = fmaf(XS, WV.w, A.w);

// ---------- dtype probe: int64 edge_index has zero high words ----------
__global__ void detect_kernel(const int* ei, int* flag) {
  __shared__ int any;
  if (threadIdx.x == 0) any = 0;
  __syncthreads();
  for (int i = threadIdx.x; i < 1024; i += blockDim.x)
    if (ei[2 * i + 1] != 0) any = 1;
  __syncthreads();
  if (threadIdx.x == 0) *flag = (any == 0) ? 1 : 0;  // 1 => int64
}

// ---------- init: zero out0 accumulator, -inf maxes, zero denoms ----------
__global__ void init_kernel(float* out0, float* e_max, float* denom, int N) {
  int total = N * F;
  for (int i = blockIdx.x * blockDim.x + threadIdx.x; i < total;
       i += gridDim.x * blockDim.x) {
    out0[i] = 0.0f;
    if (i < N) { e_max[i] = -INFINITY; denom[i] = 0.0f; }
  }
}

// ---------- xp = x @ W  (32 rows/block, thread = 4x4 tile) ----------
__global__ __launch_bounds__(256) void gemm_xp_kernel(
    const float* __restrict__ x, const float* __restrict__ W,
    float* __restrict__ xp, int N) {
  __shared__ float Ws[F * F];    // 64KB
  __shared__ float Xs[32 * F];   // 16KB
  const int tid = threadIdx.x;

  const float4* W4 = (const float4*)W;
  float4* Ws4 = (float4*)Ws;
  for (int i = tid; i < F * F / 4; i += 256) Ws4[i] = W4[i];

  const int rowbase = blockIdx.x * 32;
  const int nrows = min(32, N - rowbase);
  const float4* x4 = (const float4*)(x + (size_t)rowbase * F);
  float4* Xs4 = (float4*)Xs;
  for (int i = tid; i < nrows * (F / 4); i += 256) Xs4[i] = x4[i];
  __syncthreads();

  const int rg = tid >> 5;   // 0..7  -> rows rg*4..+3
  const int cg = tid & 31;   // cols cg*4..+3
  float4 acc[4];
  acc[0] = acc[1] = acc[2] = acc[3] = make_float4(0.f, 0.f, 0.f, 0.f);

  for (int k0 = 0; k0 < F; k0 += 4) {
    float4 wv0 = Ws4[(k0 + 0) * 32 + cg];
    float4 wv1 = Ws4[(k0 + 1) * 32 + cg];
    float4 wv2 = Ws4[(k0 + 2) * 32 + cg];
    float4 wv3 = Ws4[(k0 + 3) * 32 + cg];
#pragma unroll
    for (int r = 0; r < 4; ++r) {
      float4 xv = Xs4[(rg * 4 + r) * 32 + (k0 >> 2)];
      FMA4(acc[r], xv.x, wv0); FMA4(acc[r], xv.y, wv1);
      FMA4(acc[r], xv.z, wv2); FMA4(acc[r], xv.w, wv3);
    }
  }
#pragma unroll
  for (int r = 0; r < 4; ++r) {
    int row = rowbase + rg * 4 + r;
    if (row < N) *(float4*)(xp + (size_t)row * F + cg * 4) = acc[r];
  }
}

// ---------- alpha_s / alpha_d : one wave per row ----------
__global__ void alphas_kernel(const float* __restrict__ xp,
                              const float* __restrict__ a_s,
                              const float* __restrict__ a_d,
                              float* alpha_s, float* alpha_d, int N) {
  int wid = (int)((blockIdx.x * (long long)blockDim.x + threadIdx.x) >> 6);
  int lane = threadIdx.x & 63;
  if (wid >= N) return;
  const float* row = xp + (size_t)wid * F;
  float v0 = row[lane], v1 = row[lane + 64];
  float ps = v0 * a_s[lane] + v1 * a_s[lane + 64];
  float pd = v0 * a_d[lane] + v1 * a_d[lane + 64];
  for (int o = 32; o > 0; o >>= 1) {
    ps += __shfl_down(ps, o);
    pd += __shfl_down(pd, o);
  }
  if (lane == 0) { alpha_s[wid] = ps; alpha_d[wid] = pd; }
}

// ---------- edge pass 1: e + leaky relu, segment max ----------
__global__ void edge1_kernel(const int* ei, const float* __restrict__ alpha_s,
                             const float* __restrict__ alpha_d, float* e_arr,
                             float* e_max, const int* flag, int E, int N) {
  int i = blockIdx.x * blockDim.x + threadIdx.x;
  if (i >= E + N) return;
  int s, d;
  edge_sd(ei, i, E, *flag, s, d);
  float e = alpha_s[s] + alpha_d[d];
  e = (e >= 0.f) ? e : LEAK * e;
  e_arr[i] = e;
  atomicMaxF(&e_max[d], e);
}

// ---------- edge pass 2: exp, segment sum ----------
__global__ void edge2_kernel(const int* ei, float* e_arr,
                             const float* __restrict__ e_max, float* denom,
                             const int* flag, int E, int N) {
  int i = blockIdx.x * blockDim.x + threadIdx.x;
  if (i >= E + N) return;
  int s, d;
  edge_sd(ei, i, E, *flag, s, d);
  float ex = expf(e_arr[i] - e_max[d]);
  e_arr[i] = ex;
  atomicAdd(&denom[d], ex);
}

// ---------- edge pass 3: out[dst] += alpha * xp[src] ----------
__global__ void edge3_kernel(const int* ei, const float* __restrict__ e_arr,
                             const float* __restrict__ denom,
                             const float* __restrict__ xp, float* out0,
                             const int* flag, int E, int N) {
  long long t = (long long)blockIdx.x * blockDim.x + threadIdx.x;
  long long EN = E + N;
  if (t >= EN * 32) return;
  int e = (int)(t >> 5);
  int f = ((int)t & 31) << 2;
  int s, d;
  edge_sd(ei, e, E, *flag, s, d);
  float alpha = e_arr[e] / denom[d];
  float4 v = *(const float4*)(xp + (size_t)s * F + f);
  float* o = out0 + (size_t)d * F + f;
  atomicAdd(o + 0, alpha * v.x);
  atomicAdd(o + 1, alpha * v.y);
  atomicAdd(o + 2, alpha * v.z);
  atomicAdd(o + 3, alpha * v.w);
}

// ---------- fused MLP: h=[x|relu(xe+b)] -> relu@W1 -> relu@W2 -> @W3 -> sigmoid
// also writes x_embedded (+bias) back to out0
__global__ __launch_bounds__(256) void mlp_kernel(
    const float* __restrict__ x, float* __restrict__ xemb,
    const float* __restrict__ bias, const float* __restrict__ W1,
    const float* __restrict__ b1, const float* __restrict__ W2,
    const float* __restrict__ b2, const float* __restrict__ W3,
    const float* __restrict__ b3, float* __restrict__ out2, int N) {
  __shared__ float Hs[32 * 256];    // 32KB   input tile [x | relu(xe)]
  __shared__ float W1s[128 * 128];  // 64KB   one K-half of W1
  __shared__ float h1s[32 * 128];   // 16KB
  __shared__ float W2t[16 * 128];   // 8KB    W2 transposed [j][k]
  __shared__ float h2s[32 * 16];    // 2KB
  const int tid = threadIdx.x;
  const int nb = blockIdx.x * 32;

  // W2 transposed (tiny)
  for (int idx = tid; idx < 16 * 128; idx += 256) {
    int j2 = idx >> 7, k = idx & 127;
    W2t[idx] = W2[k * 16 + j2];
  }

  // stage H tile; write back x_embedded = xe + bias
  float4* Hs4 = (float4*)Hs;
  for (int idx = tid; idx < 32 * 64; idx += 256) {
    int r = idx >> 6, q = idx & 63;
    int node = nb + r;
    float4 v = make_float4(0.f, 0.f, 0.f, 0.f);
    if (node < N) {
      if (q < 32) {
        v = *(const float4*)(x + (size_t)node * F + q * 4);
      } else {
        int f = (q - 32) * 4;
        float4 e = *(const float4*)(xemb + (size_t)node * F + f);
        float4 bv = *(const float4*)(bias + f);
        e.x += bv.x; e.y += bv.y; e.z += bv.z; e.w += bv.w;
        *(float4*)(xemb + (size_t)node * F + f) = e;  // final output 0
        v.x = fmaxf(e.x, 0.f); v.y = fmaxf(e.y, 0.f);
        v.z = fmaxf(e.z, 0.f); v.w = fmaxf(e.w, 0.f);
      }
    }
    Hs4[idx] = v;
  }

  const int rg = tid >> 5, cg = tid & 31;
  float4 acc[4];
  acc[0] = acc[1] = acc[2] = acc[3] = make_float4(0.f, 0.f, 0.f, 0.f);
  float4* W1s4 = (float4*)W1s;

  for (int h = 0; h < 2; ++h) {
    __syncthreads();
    const float4* Wg4 = (const float4*)(W1 + (size_t)h * 128 * 128);
    for (int i = tid; i < 128 * 128 / 4; i += 256) W1s4[i] = Wg4[i];
    __syncthreads();
    for (int k0 = 0; k0 < 128; k0 += 4) {
      float4 wv0 = W1s4[(k0 + 0) * 32 + cg];
      float4 wv1 = W1s4[(k0 + 1) * 32 + cg];
      float4 wv2 = W1s4[(k0 + 2) * 32 + cg];
      float4 wv3 = W1s4[(k0 + 3) * 32 + cg];
#pragma unroll
      for (int r = 0; r < 4; ++r) {
        float4 xv = Hs4[(rg * 4 + r) * 64 + ((h * 128 + k0) >> 2)];
        FMA4(acc[r], xv.x, wv0); FMA4(acc[r], xv.y, wv1);
        FMA4(acc[r], xv.z, wv2); FMA4(acc[r], xv.w, wv3);
      }
    }
  }

  // h1 = relu(acc + b1)
  float4 bv = *(const float4*)(b1 + cg * 4);
  float4* h1s4 = (float4*)h1s;
#pragma unroll
  for (int r = 0; r < 4; ++r) {
    float4 v = acc[r];
    v.x = fmaxf(v.x + bv.x, 0.f); v.y = fmaxf(v.y + bv.y, 0.f);
    v.z = fmaxf(v.z + bv.z, 0.f); v.w = fmaxf(v.w + bv.w, 0.f);
    h1s4[(rg * 4 + r) * 32 + cg] = v;
  }
  __syncthreads();

  // layer 2: 32 nodes x 16 outs, dot-128
  float4* W2t4 = (float4*)W2t;
  for (int p = tid; p < 512; p += 256) {
    int node = p >> 4, j2 = p & 15;
    float s = 0.f;
    for (int k4 = 0; k4 < 32; ++k4) {
      float4 hv = h1s4[node * 32 + k4];
      float4 wv = W2t4[j2 * 32 + k4];
      s += hv.x * wv.x + hv.y * wv.y + hv.z * wv.z + hv.w * wv.w;
    }
    h2s[node * 16 + j2] = fmaxf(s + b2[j2], 0.f);
  }
  __syncthreads();

  // layer 3 + sigmoid
  if (tid < 64) {
    int node = tid >> 1, c = tid & 1;
    float s = b3[c];
#pragma unroll
    for (int k = 0; k < 16; ++k) s += h2s[node * 16 + k] * W3[k * 2 + c];
    float sig = 1.f / (1.f + expf(-s));
    int gn = nb + node;
    if (gn < N) out2[(size_t)gn * 2 + c] = sig;
  }
}

// ---------- launch ----------
extern "C" void kernel_launch(void* const* d_in, const int* in_sizes, int n_in,
                              void* d_out, int out_size, void* d_ws,
                              size_t ws_size, hipStream_t stream) {
  const float* x     = (const float*)d_in[0];
  const int*   ei    = (const int*)d_in[1];
  const float* W     = (const float*)d_in[2];
  const float* a_src = (const float*)d_in[3];
  const float* a_dst = (const float*)d_in[4];
  const float* bias  = (const float*)d_in[5];
  const float* W1    = (const float*)d_in[6];
  const float* b1    = (const float*)d_in[7];
  const float* W2    = (const float*)d_in[8];
  const float* b2    = (const float*)d_in[9];
  const float* W3    = (const float*)d_in[10];
  const float* b3    = (const float*)d_in[11];

  const int N = in_sizes[0] / F;
  const int E = in_sizes[1] / 2;
  const int EN = E + N;

  float* ws      = (float*)d_ws;
  float* xp      = ws;                        // N*F
  float* alpha_s = xp + (size_t)N * F;        // N
  float* alpha_d = alpha_s + N;               // N
  float* e_max   = alpha_d + N;               // N
  float* denom   = e_max + N;                 // N
  float* e_arr   = denom + N;                 // EN
  int*   flag    = (int*)(e_arr + EN);        // 1

  float* out0 = (float*)d_out;                // x_embedded [N,F]
  float* out2 = out0 + (size_t)N * F;         // sigmoid(logits) [N,2]

  detect_kernel<<<1, 256, 0, stream>>>(ei, flag);
  init_kernel<<<2048, 256, 0, stream>>>(out0, e_max, denom, N);
  gemm_xp_kernel<<<(N + 31) / 32, 256, 0, stream>>>(x, W, xp, N);
  alphas_kernel<<<(N + 3) / 4, 256, 0, stream>>>(xp, a_src, a_dst, alpha_s,
                                                 alpha_d, N);
  edge1_kernel<<<(EN + 255) / 256, 256, 0, stream>>>(ei, alpha_s, alpha_d,
                                                     e_arr, e_max, flag, E, N);
  edge2_kernel<<<(EN + 255) / 256, 256, 0, stream>>>(ei, e_arr, e_max, denom,
                                                     flag, E, N);
  edge3_kernel<<<(int)(((long long)EN * 32 + 255) / 256), 256, 0, stream>>>(
      ei, e_arr, denom, xp, out0, flag, E, N);
  mlp_kernel<<<(N + 31) / 32, 256, 0, stream>>>(x, out0, bias, W1, b1, W2, b2,
                                                W3, b3, out2, N);
}

// Round 2
// 564.797 us; speedup vs baseline: 2.8829x; 2.8829x over previous
//
#include <hip/hip_runtime.h>

#define F 128
#define LEAK 0.2f

// fetch (src,dst) for concat([edges, self-loops]) edge i
__device__ inline void edge_sd(const int* ei, int i, int E, int is64, int& s, int& d) {
  if (i < E) {
    if (is64) {
      const long long* e64 = (const long long*)ei;
      s = (int)e64[i]; d = (int)e64[E + i];
    } else {
      s = ei[i]; d = ei[E + i];
    }
  } else {
    s = d = i - E;
  }
}

#define FMA4(A, XS, WV) \
  A.x = fmaf(XS, WV.x, A.x); A.y = fmaf(XS, WV.y, A.y); \
  A.z = fmaf(XS, WV.z, A.z); A.w = fmaf(XS, WV.w, A.w);

// ---------- dtype probe: int64 edge_index has zero high words ----------
__global__ void detect_kernel(const int* ei, int* flag) {
  __shared__ int any;
  if (threadIdx.x == 0) any = 0;
  __syncthreads();
  for (int i = threadIdx.x; i < 1024; i += blockDim.x)
    if (ei[2 * i + 1] != 0) any = 1;
  __syncthreads();
  if (threadIdx.x == 0) *flag = (any == 0) ? 1 : 0;  // 1 => int64
}

// ---------- zero degree + cursor ----------
__global__ void zero_kernel(int* deg, int* cursor, int N) {
  int i = blockIdx.x * blockDim.x + threadIdx.x;
  if (i < N) { deg[i] = 0; cursor[i] = 0; }
}

// ---------- count in-degree (incl self-loops) ----------
__global__ void count_kernel(const int* ei, int* deg, const int* flag, int E, int N) {
  int i = blockIdx.x * blockDim.x + threadIdx.x;
  if (i >= E + N) return;
  int s, d;
  edge_sd(ei, i, E, *flag, s, d);
  atomicAdd(&deg[d], 1);
}

// ---------- scan phase 1: per-1024-chunk sums ----------
__global__ void scan1_kernel(const int* deg, int* partial, int N) {
  __shared__ int ts[256];
  int b = blockIdx.x, t = threadIdx.x;
  int base = b * 1024 + t * 4;
  int s = 0;
#pragma unroll
  for (int k = 0; k < 4; ++k) s += (base + k < N) ? deg[base + k] : 0;
  ts[t] = s;
  __syncthreads();
  for (int o = 128; o > 0; o >>= 1) {
    if (t < o) ts[t] += ts[t + o];
    __syncthreads();
  }
  if (t == 0) partial[b] = ts[0];
}

// ---------- scan phase 2: exclusive scan of chunk sums (nchunks <= 256) ----------
__global__ void scan2_kernel(const int* partial, int* chunk_off, int* row_start,
                             int nchunks, int N) {
  __shared__ int ts[256];
  int t = threadIdx.x;
  int v = (t < nchunks) ? partial[t] : 0;
  ts[t] = v;
  __syncthreads();
  for (int o = 1; o < 256; o <<= 1) {
    int add = (t >= o) ? ts[t - o] : 0;
    __syncthreads();
    ts[t] += add;
    __syncthreads();
  }
  if (t < nchunks) chunk_off[t] = ts[t] - v;
  if (t == nchunks - 1) row_start[N] = ts[t];  // total = E + N
}

// ---------- scan phase 3: within-chunk exclusive scan + chunk offset ----------
__global__ void scan3_kernel(const int* deg, const int* chunk_off,
                             int* row_start, int N) {
  __shared__ int ts[256];
  int b = blockIdx.x, t = threadIdx.x;
  int base = b * 1024 + t * 4;
  int v[4];
#pragma unroll
  for (int k = 0; k < 4; ++k) v[k] = (base + k < N) ? deg[base + k] : 0;
  int p1 = v[0], p2 = p1 + v[1], p3 = p2 + v[2], sum = p3 + v[3];
  ts[t] = sum;
  __syncthreads();
  for (int o = 1; o < 256; o <<= 1) {
    int add = (t >= o) ? ts[t - o] : 0;
    __syncthreads();
    ts[t] += add;
    __syncthreads();
  }
  int off = chunk_off[b] + ts[t] - sum;
  int ex[4] = {0, p1, p2, p3};
#pragma unroll
  for (int k = 0; k < 4; ++k)
    if (base + k < N) row_start[base + k] = off + ex[k];
}

// ---------- fill sorted_src buckets ----------
__global__ void fill_kernel(const int* ei, const int* row_start, int* cursor,
                            int* sorted_src, const int* flag, int E, int N) {
  int i = blockIdx.x * blockDim.x + threadIdx.x;
  if (i >= E + N) return;
  int s, d;
  edge_sd(ei, i, E, *flag, s, d);
  int p = atomicAdd(&cursor[d], 1);
  sorted_src[row_start[d] + p] = s;
}

// ---------- xp = x @ W  (32 rows/block, thread = 4x4 tile) ----------
__global__ __launch_bounds__(256) void gemm_xp_kernel(
    const float* __restrict__ x, const float* __restrict__ W,
    float* __restrict__ xp, int N) {
  __shared__ float Ws[F * F];    // 64KB
  __shared__ float Xs[32 * F];   // 16KB
  const int tid = threadIdx.x;

  const float4* W4 = (const float4*)W;
  float4* Ws4 = (float4*)Ws;
  for (int i = tid; i < F * F / 4; i += 256) Ws4[i] = W4[i];

  const int rowbase = blockIdx.x * 32;
  const int nrows = min(32, N - rowbase);
  const float4* x4 = (const float4*)(x + (size_t)rowbase * F);
  float4* Xs4 = (float4*)Xs;
  for (int i = tid; i < nrows * (F / 4); i += 256) Xs4[i] = x4[i];
  __syncthreads();

  const int rg = tid >> 5;   // 0..7  -> rows rg*4..+3
  const int cg = tid & 31;   // cols cg*4..+3
  float4 acc[4];
  acc[0] = acc[1] = acc[2] = acc[3] = make_float4(0.f, 0.f, 0.f, 0.f);

  for (int k0 = 0; k0 < F; k0 += 4) {
    float4 wv0 = Ws4[(k0 + 0) * 32 + cg];
    float4 wv1 = Ws4[(k0 + 1) * 32 + cg];
    float4 wv2 = Ws4[(k0 + 2) * 32 + cg];
    float4 wv3 = Ws4[(k0 + 3) * 32 + cg];
#pragma unroll
    for (int r = 0; r < 4; ++r) {
      float4 xv = Xs4[(rg * 4 + r) * 32 + (k0 >> 2)];
      FMA4(acc[r], xv.x, wv0); FMA4(acc[r], xv.y, wv1);
      FMA4(acc[r], xv.z, wv2); FMA4(acc[r], xv.w, wv3);
    }
  }
#pragma unroll
  for (int r = 0; r < 4; ++r) {
    int row = rowbase + rg * 4 + r;
    if (row < N) *(float4*)(xp + (size_t)row * F + cg * 4) = acc[r];
  }
}

// ---------- alpha_s / alpha_d : one wave per row ----------
__global__ void alphas_kernel(const float* __restrict__ xp,
                              const float* __restrict__ a_s,
                              const float* __restrict__ a_d,
                              float* alpha_s, float* alpha_d, int N) {
  int wid = (int)((blockIdx.x * (long long)blockDim.x + threadIdx.x) >> 6);
  int lane = threadIdx.x & 63;
  if (wid >= N) return;
  const float* row = xp + (size_t)wid * F;
  float v0 = row[lane], v1 = row[lane + 64];
  float ps = v0 * a_s[lane] + v1 * a_s[lane + 64];
  float pd = v0 * a_d[lane] + v1 * a_d[lane + 64];
  for (int o = 32; o > 0; o >>= 1) {
    ps += __shfl_down(ps, o);
    pd += __shfl_down(pd, o);
  }
  if (lane == 0) { alpha_s[wid] = ps; alpha_d[wid] = pd; }
}

// ---------- gather: one wave per dst node; softmax + weighted sum + bias ----------
__global__ __launch_bounds__(256) void gather_kernel(
    const int* __restrict__ row_start, const int* __restrict__ sorted_src,
    const float* __restrict__ alpha_s, const float* __restrict__ alpha_d,
    const float* __restrict__ xp, const float* __restrict__ bias,
    float* __restrict__ out0, int N) {
  int wid = blockIdx.x * 4 + (threadIdx.x >> 6);
  int lane = threadIdx.x & 63;
  if (wid >= N) return;
  int rs = row_start[wid], re = row_start[wid + 1];
  float ad = alpha_d[wid];

  float m = -INFINITY;
  for (int j = rs; j < re; ++j) {
    float e = alpha_s[sorted_src[j]] + ad;
    e = (e >= 0.f) ? e : LEAK * e;
    m = fmaxf(m, e);
  }
  float l = 0.f, a0 = 0.f, a1 = 0.f;
  for (int j = rs; j < re; ++j) {
    int s = sorted_src[j];
    float e = alpha_s[s] + ad;
    e = (e >= 0.f) ? e : LEAK * e;
    float w = expf(e - m);
    l += w;
    const float* row = xp + (size_t)s * F;
    a0 = fmaf(w, row[lane], a0);
    a1 = fmaf(w, row[lane + 64], a1);
  }
  float inv = 1.f / l;
  out0[(size_t)wid * F + lane] = fmaf(a0, inv, bias[lane]);
  out0[(size_t)wid * F + lane + 64] = fmaf(a1, inv, bias[lane + 64]);
}

// ---------- fused MLP: h=[x|relu(xe)] -> relu@W1 -> relu@W2 -> @W3 -> sigmoid
__global__ __launch_bounds__(256) void mlp_kernel(
    const float* __restrict__ x, const float* __restrict__ xemb,
    const float* __restrict__ W1, const float* __restrict__ b1,
    const float* __restrict__ W2, const float* __restrict__ b2,
    const float* __restrict__ W3, const float* __restrict__ b3,
    float* __restrict__ out2, int N) {
  __shared__ float Hs[32 * 256];    // 32KB   input tile [x | relu(xe)]
  __shared__ float W1s[128 * 128];  // 64KB   one K-half of W1
  __shared__ float h1s[32 * 128];   // 16KB
  __shared__ float W2t[16 * 128];   // 8KB    W2 transposed [j][k]
  __shared__ float h2s[32 * 16];    // 2KB
  const int tid = threadIdx.x;
  const int nb = blockIdx.x * 32;

  // W2 transposed (tiny)
  for (int idx = tid; idx < 16 * 128; idx += 256) {
    int j2 = idx >> 7, k = idx & 127;
    W2t[idx] = W2[k * 16 + j2];
  }

  // stage H tile
  float4* Hs4 = (float4*)Hs;
  for (int idx = tid; idx < 32 * 64; idx += 256) {
    int r = idx >> 6, q = idx & 63;
    int node = nb + r;
    float4 v = make_float4(0.f, 0.f, 0.f, 0.f);
    if (node < N) {
      if (q < 32) {
        v = *(const float4*)(x + (size_t)node * F + q * 4);
      } else {
        float4 e = *(const float4*)(xemb + (size_t)node * F + (q - 32) * 4);
        v.x = fmaxf(e.x, 0.f); v.y = fmaxf(e.y, 0.f);
        v.z = fmaxf(e.z, 0.f); v.w = fmaxf(e.w, 0.f);
      }
    }
    Hs4[idx] = v;
  }

  const int rg = tid >> 5, cg = tid & 31;
  float4 acc[4];
  acc[0] = acc[1] = acc[2] = acc[3] = make_float4(0.f, 0.f, 0.f, 0.f);
  float4* W1s4 = (float4*)W1s;

  for (int h = 0; h < 2; ++h) {
    __syncthreads();
    const float4* Wg4 = (const float4*)(W1 + (size_t)h * 128 * 128);
    for (int i = tid; i < 128 * 128 / 4; i += 256) W1s4[i] = Wg4[i];
    __syncthreads();
    for (int k0 = 0; k0 < 128; k0 += 4) {
      float4 wv0 = W1s4[(k0 + 0) * 32 + cg];
      float4 wv1 = W1s4[(k0 + 1) * 32 + cg];
      float4 wv2 = W1s4[(k0 + 2) * 32 + cg];
      float4 wv3 = W1s4[(k0 + 3) * 32 + cg];
#pragma unroll
      for (int r = 0; r < 4; ++r) {
        float4 xv = Hs4[(rg * 4 + r) * 64 + ((h * 128 + k0) >> 2)];
        FMA4(acc[r], xv.x, wv0); FMA4(acc[r], xv.y, wv1);
        FMA4(acc[r], xv.z, wv2); FMA4(acc[r], xv.w, wv3);
      }
    }
  }

  // h1 = relu(acc + b1)
  float4 bv = *(const float4*)(b1 + cg * 4);
  float4* h1s4 = (float4*)h1s;
#pragma unroll
  for (int r = 0; r < 4; ++r) {
    float4 v = acc[r];
    v.x = fmaxf(v.x + bv.x, 0.f); v.y = fmaxf(v.y + bv.y, 0.f);
    v.z = fmaxf(v.z + bv.z, 0.f); v.w = fmaxf(v.w + bv.w, 0.f);
    h1s4[(rg * 4 + r) * 32 + cg] = v;
  }
  __syncthreads();

  // layer 2: 32 nodes x 16 outs, dot-128
  float4* W2t4 = (float4*)W2t;
  for (int p = tid; p < 512; p += 256) {
    int node = p >> 4, j2 = p & 15;
    float s = 0.f;
    for (int k4 = 0; k4 < 32; ++k4) {
      float4 hv = h1s4[node * 32 + k4];
      float4 wv = W2t4[j2 * 32 + k4];
      s += hv.x * wv.x + hv.y * wv.y + hv.z * wv.z + hv.w * wv.w;
    }
    h2s[node * 16 + j2] = fmaxf(s + b2[j2], 0.f);
  }
  __syncthreads();

  // layer 3 + sigmoid
  if (tid < 64) {
    int node = tid >> 1, c = tid & 1;
    float s = b3[c];
#pragma unroll
    for (int k = 0; k < 16; ++k) s += h2s[node * 16 + k] * W3[k * 2 + c];
    float sig = 1.f / (1.f + expf(-s));
    int gn = nb + node;
    if (gn < N) out2[(size_t)gn * 2 + c] = sig;
  }
}

// ---------- launch ----------
extern "C" void kernel_launch(void* const* d_in, const int* in_sizes, int n_in,
                              void* d_out, int out_size, void* d_ws,
                              size_t ws_size, hipStream_t stream) {
  const float* x     = (const float*)d_in[0];
  const int*   ei    = (const int*)d_in[1];
  const float* W     = (const float*)d_in[2];
  const float* a_src = (const float*)d_in[3];
  const float* a_dst = (const float*)d_in[4];
  const float* bias  = (const float*)d_in[5];
  const float* W1    = (const float*)d_in[6];
  const float* b1    = (const float*)d_in[7];
  const float* W2    = (const float*)d_in[8];
  const float* b2    = (const float*)d_in[9];
  const float* W3    = (const float*)d_in[10];
  const float* b3    = (const float*)d_in[11];

  const int N = in_sizes[0] / F;
  const int E = in_sizes[1] / 2;
  const int EN = E + N;
  const int nchunks = (N + 1023) / 1024;

  float* ws      = (float*)d_ws;
  float* xp      = ws;                          // N*F
  float* alpha_s = xp + (size_t)N * F;          // N
  float* alpha_d = alpha_s + N;                 // N
  int* deg        = (int*)(alpha_d + N);        // N
  int* row_start  = deg + N;                    // N+1
  int* cursor     = row_start + N + 1;          // N
  int* partial    = cursor + N;                 // 256
  int* chunk_off  = partial + 256;              // 256
  int* sorted_src = chunk_off + 256;            // EN
  int* flag       = sorted_src + EN;            // 1

  float* out0 = (float*)d_out;                  // x_embedded [N,F]
  float* out2 = out0 + (size_t)N * F;           // sigmoid(logits) [N,2]

  detect_kernel<<<1, 256, 0, stream>>>(ei, flag);
  zero_kernel<<<(N + 255) / 256, 256, 0, stream>>>(deg, cursor, N);
  count_kernel<<<(EN + 255) / 256, 256, 0, stream>>>(ei, deg, flag, E, N);
  scan1_kernel<<<nchunks, 256, 0, stream>>>(deg, partial, N);
  scan2_kernel<<<1, 256, 0, stream>>>(partial, chunk_off, row_start, nchunks, N);
  scan3_kernel<<<nchunks, 256, 0, stream>>>(deg, chunk_off, row_start, N);
  fill_kernel<<<(EN + 255) / 256, 256, 0, stream>>>(ei, row_start, cursor,
                                                    sorted_src, flag, E, N);
  gemm_xp_kernel<<<(N + 31) / 32, 256, 0, stream>>>(x, W, xp, N);
  alphas_kernel<<<(N + 3) / 4, 256, 0, stream>>>(xp, a_src, a_dst, alpha_s,
                                                 alpha_d, N);
  gather_kernel<<<(N + 3) / 4, 256, 0, stream>>>(row_start, sorted_src, alpha_s,
                                                 alpha_d, xp, bias, out0, N);
  mlp_kernel<<<(N + 31) / 32, 256, 0, stream>>>(x, out0, W1, b1, W2, b2, W3, b3,
                                                out2, N);
}

// Round 3
// 295.734 us; speedup vs baseline: 5.5058x; 1.9098x over previous
//
#include <hip/hip_runtime.h>

#define F 128
#define LEAK 0.2f

typedef __attribute__((ext_vector_type(8))) short bf16x8;
typedef __attribute__((ext_vector_type(4))) float f32x4;

union FragU { bf16x8 v; unsigned u[4]; };

__device__ inline unsigned f2bf(float f) {
  unsigned u = __float_as_uint(f);
  return (u + 0x7FFFu + ((u >> 16) & 1u)) >> 16;  // RNE
}
__device__ inline unsigned packbf(float lo, float hi) {
  return f2bf(lo) | (f2bf(hi) << 16);
}

// fetch (src,dst) for concat([edges, self-loops]) edge i
__device__ inline void edge_sd(const int* ei, int i, int E, int is64, int& s, int& d) {
  if (i < E) {
    if (is64) {
      const long long* e64 = (const long long*)ei;
      s = (int)e64[i]; d = (int)e64[E + i];
    } else {
      s = ei[i]; d = ei[E + i];
    }
  } else {
    s = d = i - E;
  }
}

// ---------- dtype probe: int64 edge_index has zero high words ----------
__global__ void detect_kernel(const int* ei, int* flag) {
  __shared__ int any;
  if (threadIdx.x == 0) any = 0;
  __syncthreads();
  for (int i = threadIdx.x; i < 1024; i += blockDim.x)
    if (ei[2 * i + 1] != 0) any = 1;
  __syncthreads();
  if (threadIdx.x == 0) *flag = (any == 0) ? 1 : 0;  // 1 => int64
}

// ---------- zero degree + cursor ----------
__global__ void zero_kernel(int* deg, int* cursor, int N) {
  int i = blockIdx.x * blockDim.x + threadIdx.x;
  if (i < N) { deg[i] = 0; cursor[i] = 0; }
}

// ---------- count in-degree (incl self-loops) ----------
__global__ void count_kernel(const int* ei, int* deg, const int* flag, int E, int N) {
  int i = blockIdx.x * blockDim.x + threadIdx.x;
  if (i >= E + N) return;
  int s, d;
  edge_sd(ei, i, E, *flag, s, d);
  atomicAdd(&deg[d], 1);
}

// ---------- scan phase 1: per-1024-chunk sums ----------
__global__ void scan1_kernel(const int* deg, int* partial, int N) {
  __shared__ int ts[256];
  int b = blockIdx.x, t = threadIdx.x;
  int base = b * 1024 + t * 4;
  int s = 0;
#pragma unroll
  for (int k = 0; k < 4; ++k) s += (base + k < N) ? deg[base + k] : 0;
  ts[t] = s;
  __syncthreads();
  for (int o = 128; o > 0; o >>= 1) {
    if (t < o) ts[t] += ts[t + o];
    __syncthreads();
  }
  if (t == 0) partial[b] = ts[0];
}

// ---------- scan phase 2: exclusive scan of chunk sums (nchunks <= 256) ----------
__global__ void scan2_kernel(const int* partial, int* chunk_off, int* row_start,
                             int nchunks, int N) {
  __shared__ int ts[256];
  int t = threadIdx.x;
  int v = (t < nchunks) ? partial[t] : 0;
  ts[t] = v;
  __syncthreads();
  for (int o = 1; o < 256; o <<= 1) {
    int add = (t >= o) ? ts[t - o] : 0;
    __syncthreads();
    ts[t] += add;
    __syncthreads();
  }
  if (t < nchunks) chunk_off[t] = ts[t] - v;
  if (t == nchunks - 1) row_start[N] = ts[t];  // total = E + N
}

// ---------- scan phase 3: within-chunk exclusive scan + chunk offset ----------
__global__ void scan3_kernel(const int* deg, const int* chunk_off,
                             int* row_start, int N) {
  __shared__ int ts[256];
  int b = blockIdx.x, t = threadIdx.x;
  int base = b * 1024 + t * 4;
  int v[4];
#pragma unroll
  for (int k = 0; k < 4; ++k) v[k] = (base + k < N) ? deg[base + k] : 0;
  int p1 = v[0], p2 = p1 + v[1], p3 = p2 + v[2], sum = p3 + v[3];
  ts[t] = sum;
  __syncthreads();
  for (int o = 1; o < 256; o <<= 1) {
    int add = (t >= o) ? ts[t - o] : 0;
    __syncthreads();
    ts[t] += add;
    __syncthreads();
  }
  int off = chunk_off[b] + ts[t] - sum;
  int ex[4] = {0, p1, p2, p3};
#pragma unroll
  for (int k = 0; k < 4; ++k)
    if (base + k < N) row_start[base + k] = off + ex[k];
}

// ---------- fill sorted_src buckets ----------
__global__ void fill_kernel(const int* ei, const int* row_start, int* cursor,
                            int* sorted_src, const int* flag, int E, int N) {
  int i = blockIdx.x * blockDim.x + threadIdx.x;
  if (i >= E + N) return;
  int s, d;
  edge_sd(ei, i, E, *flag, s, d);
  int p = atomicAdd(&cursor[d], 1);
  sorted_src[row_start[d] + p] = s;
}

// ---------- xp = x @ W via bf16 MFMA; fused alpha_s/alpha_d ----------
// grid-stride over 128-row tiles; 512 threads = 8 waves, wave w owns 16 rows.
__global__ __launch_bounds__(512) void gemm_xp_kernel(
    const float* __restrict__ x, const float* __restrict__ W,
    const float* __restrict__ a_src, const float* __restrict__ a_dst,
    float* __restrict__ xp, float* __restrict__ alpha_s,
    float* __restrict__ alpha_d, int N, int ntiles) {
  __shared__ char Wt[128 * 256];  // [n][k] bf16, swizzled, 32KB
  const int tid = threadIdx.x;

  // stage W^T bf16 (pack 2 k per dword)
  for (int idx = tid; idx < 128 * 64; idx += 512) {
    int n = idx & 127, k = (idx >> 7) * 2;
    unsigned p = packbf(W[(size_t)k * 128 + n], W[(size_t)(k + 1) * 128 + n]);
    *(unsigned*)(Wt + n * 256 + ((k * 2) ^ ((n & 7) << 4))) = p;
  }
  __syncthreads();

  const int w = tid >> 6, l = tid & 63;
  const int lr = l & 15, lg = l >> 4;
  float asv[8], adv[8];
#pragma unroll
  for (int f = 0; f < 8; ++f) {
    asv[f] = a_src[f * 16 + lr];
    adv[f] = a_dst[f * 16 + lr];
  }

  for (int t = blockIdx.x; t < ntiles; t += gridDim.x) {
    const int rbase = t * 128 + w * 16;
    const int rc = min(rbase + lr, N - 1);
    const float* xrow = x + (size_t)rc * 128;

    FragU a[4];
#pragma unroll
    for (int ks = 0; ks < 4; ++ks) {
      float4 p0 = *(const float4*)(xrow + ks * 32 + lg * 8);
      float4 p1 = *(const float4*)(xrow + ks * 32 + lg * 8 + 4);
      a[ks].u[0] = packbf(p0.x, p0.y); a[ks].u[1] = packbf(p0.z, p0.w);
      a[ks].u[2] = packbf(p1.x, p1.y); a[ks].u[3] = packbf(p1.z, p1.w);
    }

    f32x4 acc[8];
#pragma unroll
    for (int f = 0; f < 8; ++f) acc[f] = (f32x4){0.f, 0.f, 0.f, 0.f};

#pragma unroll
    for (int ks = 0; ks < 4; ++ks) {
#pragma unroll
      for (int f = 0; f < 8; ++f) {
        int n = f * 16 + lr;
        FragU bfr;
        bfr.v = *(const bf16x8*)(Wt + n * 256 +
                                 ((ks * 64 + lg * 16) ^ ((n & 7) << 4)));
        acc[f] = __builtin_amdgcn_mfma_f32_16x16x32_bf16(a[ks].v, bfr.v,
                                                         acc[f], 0, 0, 0);
      }
    }

    // store xp + fused alpha reductions
#pragma unroll
    for (int r = 0; r < 4; ++r) {
      int orow = rbase + lg * 4 + r;
      float ps = 0.f, pd = 0.f;
      bool ok = (orow < N);
#pragma unroll
      for (int f = 0; f < 8; ++f) {
        float v = acc[f][r];
        ps = fmaf(v, asv[f], ps);
        pd = fmaf(v, adv[f], pd);
        if (ok) xp[(size_t)orow * 128 + f * 16 + lr] = v;
      }
#pragma unroll
      for (int m = 1; m < 16; m <<= 1) {
        ps += __shfl_xor(ps, m);
        pd += __shfl_xor(pd, m);
      }
      if (ok && lr == 0) alpha_s[orow] = ps;
      if (ok && lr == 1) alpha_d[orow] = pd;
    }
  }
}

// ---------- gather: one wave per dst node; softmax + weighted sum + bias ----------
__global__ __launch_bounds__(256) void gather_kernel(
    const int* __restrict__ row_start, const int* __restrict__ sorted_src,
    const float* __restrict__ alpha_s, const float* __restrict__ alpha_d,
    const float* __restrict__ xp, const float* __restrict__ bias,
    float* __restrict__ out0, int N) {
  int wid = blockIdx.x * 4 + (threadIdx.x >> 6);
  int lane = threadIdx.x & 63;
  if (wid >= N) return;
  int rs = row_start[wid], re = row_start[wid + 1];
  float ad = alpha_d[wid];

  float m = -INFINITY;
  for (int j = rs; j < re; ++j) {
    float e = alpha_s[sorted_src[j]] + ad;
    e = (e >= 0.f) ? e : LEAK * e;
    m = fmaxf(m, e);
  }
  float l = 0.f, a0 = 0.f, a1 = 0.f;
  for (int j = rs; j < re; ++j) {
    int s = sorted_src[j];
    float e = alpha_s[s] + ad;
    e = (e >= 0.f) ? e : LEAK * e;
    float w = expf(e - m);
    l += w;
    const float* row = xp + (size_t)s * F;
    a0 = fmaf(w, row[lane], a0);
    a1 = fmaf(w, row[lane + 64], a1);
  }
  float inv = 1.f / l;
  out0[(size_t)wid * F + lane] = fmaf(a0, inv, bias[lane]);
  out0[(size_t)wid * F + lane + 64] = fmaf(a1, inv, bias[lane + 64]);
}

// ---------- fused MLP via bf16 MFMA ----------
// h=[x|relu(xemb)] (K=256) @ W1 -> relu -> @W2 -> relu -> @W3 -> sigmoid
// 512 threads = 8 waves; 128-row tiles grid-stride; wave w owns rows w*16..+15.
__global__ __launch_bounds__(512) void mlp_kernel(
    const float* __restrict__ x, const float* __restrict__ xemb,
    const float* __restrict__ W1, const float* __restrict__ b1,
    const float* __restrict__ W2, const float* __restrict__ b2,
    const float* __restrict__ W3, const float* __restrict__ b3,
    float* __restrict__ out2, int N, int ntiles) {
  __shared__ char W1t[128 * 512];  // [n][k] bf16 swizzled, 64KB
  __shared__ char W2t[16 * 256];   // [n][k] bf16 swizzled, 4KB
  __shared__ char h1s[128 * 256];  // [row][k] bf16 swizzled, 32KB (per-wave regions)
  const int tid = threadIdx.x;

  for (int idx = tid; idx < 128 * 128; idx += 512) {
    int n = idx & 127, k = (idx >> 7) * 2;
    unsigned p = packbf(W1[(size_t)k * 128 + n], W1[(size_t)(k + 1) * 128 + n]);
    *(unsigned*)(W1t + n * 512 + ((k * 2) ^ ((n & 7) << 4))) = p;
  }
  for (int idx = tid; idx < 16 * 64; idx += 512) {
    int n = idx & 15, k = (idx >> 4) * 2;
    unsigned p = packbf(W2[(size_t)k * 16 + n], W2[(size_t)(k + 1) * 16 + n]);
    *(unsigned*)(W2t + n * 256 + ((k * 2) ^ ((n & 7) << 4))) = p;
  }
  __syncthreads();

  const int w = tid >> 6, l = tid & 63;
  const int lr = l & 15, lg = l >> 4;
  float b1v[8];
#pragma unroll
  for (int f = 0; f < 8; ++f) b1v[f] = b1[f * 16 + lr];
  const float b2v = b2[lr];
  const float w30 = W3[lr * 2 + 0], w31 = W3[lr * 2 + 1];
  const float b30 = b3[0], b31 = b3[1];

  for (int t = blockIdx.x; t < ntiles; t += gridDim.x) {
    const int rbase = t * 128 + w * 16;
    const int rc = min(rbase + lr, N - 1);
    const float* xrow = x + (size_t)rc * 128;
    const float* erow = xemb + (size_t)rc * 128;

    // ---- layer 1: A direct from global (k<128: x, k>=128: relu(xemb)) ----
    FragU a[8];
#pragma unroll
    for (int ks = 0; ks < 8; ++ks) {
      const float* src = (ks < 4) ? (xrow + ks * 32 + lg * 8)
                                  : (erow + (ks - 4) * 32 + lg * 8);
      float4 p0 = *(const float4*)(src);
      float4 p1 = *(const float4*)(src + 4);
      if (ks >= 4) {
        p0.x = fmaxf(p0.x, 0.f); p0.y = fmaxf(p0.y, 0.f);
        p0.z = fmaxf(p0.z, 0.f); p0.w = fmaxf(p0.w, 0.f);
        p1.x = fmaxf(p1.x, 0.f); p1.y = fmaxf(p1.y, 0.f);
        p1.z = fmaxf(p1.z, 0.f); p1.w = fmaxf(p1.w, 0.f);
      }
      a[ks].u[0] = packbf(p0.x, p0.y); a[ks].u[1] = packbf(p0.z, p0.w);
      a[ks].u[2] = packbf(p1.x, p1.y); a[ks].u[3] = packbf(p1.z, p1.w);
    }

    f32x4 acc[8];
#pragma unroll
    for (int f = 0; f < 8; ++f) acc[f] = (f32x4){0.f, 0.f, 0.f, 0.f};

#pragma unroll
    for (int ks = 0; ks < 8; ++ks) {
#pragma unroll
      for (int f = 0; f < 8; ++f) {
        int n = f * 16 + lr;
        FragU bfr;
        bfr.v = *(const bf16x8*)(W1t + n * 512 +
                                 ((ks * 64 + lg * 16) ^ ((n & 7) << 4)));
        acc[f] = __builtin_amdgcn_mfma_f32_16x16x32_bf16(a[ks].v, bfr.v,
                                                         acc[f], 0, 0, 0);
      }
    }

    // h1 = relu(acc + b1) -> per-wave LDS region (bf16, swizzled)
#pragma unroll
    for (int f = 0; f < 8; ++f) {
      int col = f * 16 + lr;
#pragma unroll
      for (int r = 0; r < 4; ++r) {
        int hrow = w * 16 + lg * 4 + r;
        float v = fmaxf(acc[f][r] + b1v[f], 0.f);
        *(unsigned short*)(h1s + hrow * 256 +
                           ((col * 2) ^ ((hrow & 7) << 4))) =
            (unsigned short)f2bf(v);
      }
    }

    // ---- layer 2: wave's 16 rows x 16 cols, K=128 ----
    f32x4 acc2 = (f32x4){0.f, 0.f, 0.f, 0.f};
#pragma unroll
    for (int ks = 0; ks < 4; ++ks) {
      int hrow = w * 16 + lr;
      FragU af, bfr;
      af.v = *(const bf16x8*)(h1s + hrow * 256 +
                              ((ks * 64 + lg * 16) ^ ((hrow & 7) << 4)));
      bfr.v = *(const bf16x8*)(W2t + lr * 256 +
                               ((ks * 64 + lg * 16) ^ ((lr & 7) << 4)));
      acc2 = __builtin_amdgcn_mfma_f32_16x16x32_bf16(af.v, bfr.v, acc2, 0, 0, 0);
    }

    // ---- layer 3 + sigmoid: quarter-wave shuffle reduce over 16 cols ----
#pragma unroll
    for (int r = 0; r < 4; ++r) {
      float h2 = fmaxf(acc2[r] + b2v, 0.f);
      float t0 = h2 * w30, t1 = h2 * w31;
#pragma unroll
      for (int m = 1; m < 16; m <<= 1) {
        t0 += __shfl_xor(t0, m);
        t1 += __shfl_xor(t1, m);
      }
      int orow = rbase + lg * 4 + r;
      if (orow < N && lr < 2) {
        float s = (lr == 0) ? (t0 + b30) : (t1 + b31);
        out2[(size_t)orow * 2 + lr] = 1.f / (1.f + expf(-s));
      }
    }
  }
}

// ---------- launch ----------
extern "C" void kernel_launch(void* const* d_in, const int* in_sizes, int n_in,
                              void* d_out, int out_size, void* d_ws,
                              size_t ws_size, hipStream_t stream) {
  const float* x     = (const float*)d_in[0];
  const int*   ei    = (const int*)d_in[1];
  const float* W     = (const float*)d_in[2];
  const float* a_src = (const float*)d_in[3];
  const float* a_dst = (const float*)d_in[4];
  const float* bias  = (const float*)d_in[5];
  const float* W1    = (const float*)d_in[6];
  const float* b1    = (const float*)d_in[7];
  const float* W2    = (const float*)d_in[8];
  const float* b2    = (const float*)d_in[9];
  const float* W3    = (const float*)d_in[10];
  const float* b3    = (const float*)d_in[11];

  const int N = in_sizes[0] / F;
  const int E = in_sizes[1] / 2;
  const int EN = E + N;
  const int nchunks = (N + 1023) / 1024;
  const int ntiles = (N + 127) / 128;

  float* ws      = (float*)d_ws;
  float* xp      = ws;                          // N*F
  float* alpha_s = xp + (size_t)N * F;          // N
  float* alpha_d = alpha_s + N;                 // N
  int* deg        = (int*)(alpha_d + N);        // N
  int* row_start  = deg + N;                    // N+1
  int* cursor     = row_start + N + 1;          // N
  int* partial    = cursor + N;                 // 256
  int* chunk_off  = partial + 256;              // 256
  int* sorted_src = chunk_off + 256;            // EN
  int* flag       = sorted_src + EN;            // 1

  float* out0 = (float*)d_out;                  // x_embedded [N,F]
  float* out2 = out0 + (size_t)N * F;           // sigmoid(logits) [N,2]

  detect_kernel<<<1, 256, 0, stream>>>(ei, flag);
  zero_kernel<<<(N + 255) / 256, 256, 0, stream>>>(deg, cursor, N);
  count_kernel<<<(EN + 255) / 256, 256, 0, stream>>>(ei, deg, flag, E, N);
  scan1_kernel<<<nchunks, 256, 0, stream>>>(deg, partial, N);
  scan2_kernel<<<1, 256, 0, stream>>>(partial, chunk_off, row_start, nchunks, N);
  scan3_kernel<<<nchunks, 256, 0, stream>>>(deg, chunk_off, row_start, N);
  fill_kernel<<<(EN + 255) / 256, 256, 0, stream>>>(ei, row_start, cursor,
                                                    sorted_src, flag, E, N);
  gemm_xp_kernel<<<512, 512, 0, stream>>>(x, W, a_src, a_dst, xp, alpha_s,
                                          alpha_d, N, ntiles);
  gather_kernel<<<(N + 3) / 4, 256, 0, stream>>>(row_start, sorted_src, alpha_s,
                                                 alpha_d, xp, bias, out0, N);
  mlp_kernel<<<256, 512, 0, stream>>>(x, out0, W1, b1, W2, b2, W3, b3, out2, N,
                                      ntiles);
}